// Round 5
// baseline (87.739 us; speedup 1.0000x reference)
//
#include <hip/hip_runtime.h>
#include <hip/hip_bf16.h>

#define D_IN  1024
#define D_H   512
#define L2E2  2.885390081777927f   // 2*log2(e)
#define ECLAMP 15.0f               // exp2-arg clamp: e in [2^-15, 2^15]

typedef _Float16 half8 __attribute__((ext_vector_type(8)));
typedef _Float16 half4v __attribute__((ext_vector_type(4)));
typedef float f32x4 __attribute__((ext_vector_type(4)));

// ---------------------------------------------------------------------------
// cvt: V (1024x1024 f32) -> Vh f16 ; [Wh;Wm] (1024x1024 f32) -> Wf f16
// ---------------------------------------------------------------------------
__global__ __launch_bounds__(256) void cvt_kernel(
    const float* __restrict__ V,
    const float* __restrict__ Wh, const float* __restrict__ Wm,
    _Float16* __restrict__ Vh, _Float16* __restrict__ Wf)
{
  const int idx = blockIdx.x * 256 + threadIdx.x;   // 0..262143 float4s
  {
    float4 x = ((const float4*)V)[idx];
    half4v o = { (_Float16)x.x, (_Float16)x.y, (_Float16)x.z, (_Float16)x.w };
    ((half4v*)Vh)[idx] = o;
  }
  {
    const float4* p = (idx < 131072) ? ((const float4*)Wh + idx)
                                     : ((const float4*)Wm + (idx - 131072));
    float4 x = *p;
    half4v o = { (_Float16)x.x, (_Float16)x.y, (_Float16)x.z, (_Float16)x.w };
    ((half4v*)Wf)[idx] = o;
  }
}

// ---------------------------------------------------------------------------
// proj via MFMA: C[i][j] = exp2(clamp((V[i,:].Wrow_j + bias_j)*2log2e, +-15))
// 32x64 block tile (i x j), 512 blocks = 2/CU, 4 waves (2i x 2j),
// per wave 16x32 = 2 MFMA tiles; direct global fragment loads (L2-resident).
// ---------------------------------------------------------------------------
__global__ __launch_bounds__(256) void proj_mfma_kernel(
    const _Float16* __restrict__ Vh, const _Float16* __restrict__ Wf,
    const float* __restrict__ bh, const float* __restrict__ bm,
    float* __restrict__ C)
{
  const int tid  = threadIdx.x;
  const int lane = tid & 63;
  const int wid  = tid >> 6;          // 0..3
  const int wi   = wid >> 1, wj = wid & 1;
  const int i0   = (blockIdx.x & 31) * 32;
  const int j0   = (blockIdx.x >> 5) * 64;
  const int r16  = lane & 15;
  const int kg   = lane >> 4;         // k-group 0..3

  const _Float16* A0 = Vh + (size_t)(i0 + 16*wi + r16) * 1024 + kg*8;
  const _Float16* B0 = Wf + (size_t)(j0 + 32*wj + r16) * 1024 + kg*8;
  const _Float16* B1 = B0 + 16 * 1024;

  f32x4 acc0 = {0.f,0.f,0.f,0.f}, acc1 = acc0;
  #pragma unroll 8
  for (int k0 = 0; k0 < D_IN; k0 += 32) {
    half8 a  = *(const half8*)(A0 + k0);
    half8 b0 = *(const half8*)(B0 + k0);
    half8 b1 = *(const half8*)(B1 + k0);
    acc0 = __builtin_amdgcn_mfma_f32_16x16x32_f16(a, b0, acc0, 0, 0, 0);
    acc1 = __builtin_amdgcn_mfma_f32_16x16x32_f16(a, b1, acc1, 0, 0, 0);
  }

  const float* biasp = (j0 < D_H) ? (bh + j0) : (bm + (j0 - D_H));
  // C/D layout (m89-verified): col = lane&15, row = (lane>>4)*4 + reg
  #pragma unroll
  for (int fj = 0; fj < 2; ++fj) {
    const f32x4 acc = fj ? acc1 : acc0;
    const int jl = 32*wj + 16*fj + r16;
    const float bias = biasp[jl];
    #pragma unroll
    for (int rr = 0; rr < 4; ++rr) {
      const int il = 16*wi + 4*kg + rr;
      float x = (acc[rr] + bias) * L2E2;
      x = fminf(fmaxf(x, -ECLAMP), ECLAMP);
      C[(size_t)(i0 + il) * 1024 + j0 + jl] = __builtin_amdgcn_exp2f(x);
    }
  }
}

// ---------------------------------------------------------------------------
// proj fallback (fp32 vector GEMM) when ws is too small for f16 staging.
// ---------------------------------------------------------------------------
__global__ __launch_bounds__(256) void proj_kernel(
    const float* __restrict__ V,
    const float* __restrict__ Wh, const float* __restrict__ bh,
    const float* __restrict__ Wm, const float* __restrict__ bm,
    float* __restrict__ C)
{
  __shared__ float As[16][68];
  __shared__ float Bs[16][68];

  const int tid = threadIdx.x;
  const int bi  = blockIdx.x & 15;
  const int bj  = blockIdx.x >> 4;
  const int i0  = bi * 64, j0 = bj * 64;
  const int ti  = tid >> 4, tj = tid & 15;
  const int sr  = tid >> 2;
  const int sk  = (tid & 3) << 2;

  const float* Wbase = (j0 < D_H) ? (Wh + (size_t)j0 * D_IN)
                                  : (Wm + (size_t)(j0 - D_H) * D_IN);
  const float* biasp = (j0 < D_H) ? (bh + j0) : (bm + (j0 - D_H));

  const float* arow = V     + (size_t)(i0 + sr) * D_IN + sk;
  const float* brow = Wbase + (size_t)sr        * D_IN + sk;

  float acc[4][4] = {};
  for (int k0 = 0; k0 < D_IN; k0 += 16) {
    float4 av = *(const float4*)(arow + k0);
    float4 bv = *(const float4*)(brow + k0);
    As[sk+0][sr] = av.x; As[sk+1][sr] = av.y; As[sk+2][sr] = av.z; As[sk+3][sr] = av.w;
    Bs[sk+0][sr] = bv.x; Bs[sk+1][sr] = bv.y; Bs[sk+2][sr] = bv.z; Bs[sk+3][sr] = bv.w;
    __syncthreads();
    #pragma unroll
    for (int kk = 0; kk < 16; ++kk) {
      float4 a = *(const float4*)&As[kk][4*ti];
      float4 b = *(const float4*)&Bs[kk][4*tj];
      #pragma unroll
      for (int x = 0; x < 4; ++x)
        #pragma unroll
        for (int y = 0; y < 4; ++y)
          acc[x][y] = fmaf((&a.x)[x], (&b.x)[y], acc[x][y]);
    }
    __syncthreads();
  }

  const int jl = 4 * tj;
  #pragma unroll
  for (int aa = 0; aa < 4; ++aa) {
    const int i = i0 + 4*ti + aa;
    float4 o;
    #pragma unroll
    for (int bb = 0; bb < 4; ++bb) {
      float x = (acc[aa][bb] + biasp[jl+bb]) * L2E2;
      x = fminf(fmaxf(x, -ECLAMP), ECLAMP);
      (&o.x)[bb] = __builtin_amdgcn_exp2f(x);
    }
    *(float4*)(C + (size_t)i * 1024 + j0 + jl) = o;
  }
}

// ---------------------------------------------------------------------------
// score: out[i][j] = b2 + sum(w2) - 2 * sum_k w2[k]/(1 + Eh[i,k]*Em[j,k])
// 32x32 tile/block, 2x2/thread, 4-way k-fold (1 rcp / 4 k / output).
// Double-buffered LDS (1 barrier per chunk), stride-34 rows (2-way banks).
// ---------------------------------------------------------------------------
__global__ __launch_bounds__(256) void score_kernel(
    const float* __restrict__ C,
    const float* __restrict__ w2,
    const float* __restrict__ b2,
    float* __restrict__ out)
{
  __shared__ float hs[2][32][34];
  __shared__ float ms[2][32][34];
  __shared__ float wred[4];

  const int tid = threadIdx.x;
  const int bi  = blockIdx.x & 31;
  const int bj  = blockIdx.x >> 5;
  const int i0  = bi * 32, j0 = bj * 32;
  const int ti  = tid >> 4, tj = tid & 15;   // 16x16 threads, 2x2 outputs
  const int sr  = tid >> 3;                  // staging row 0..31
  const int sk  = (tid & 7) << 2;            // staging k 0..28

  // block-reduce sum(w2)
  float sw = 0.f;
  for (int t = tid; t < D_H; t += 256) sw += w2[t];
  #pragma unroll
  for (int off = 32; off > 0; off >>= 1) sw += __shfl_down(sw, off, 64);
  if ((tid & 63) == 0) wred[tid >> 6] = sw;

  const float* hrow = C + (size_t)(i0 + sr) * 1024 + sk;         // Eh cols [0,512)
  const float* mrow = C + (size_t)(j0 + sr) * 1024 + D_H + sk;   // Em cols [512,1024)

  // preload chunk 0
  float4 hv = *(const float4*)(hrow);
  float4 mv = *(const float4*)(mrow);

  float a00 = 0.f, a01 = 0.f, a10 = 0.f, a11 = 0.f;
  int p = 0;

  for (int k0 = 0; k0 < D_H; k0 += 32) {
    // stage current chunk (float2 stores: stride-34 rows are 8B-aligned)
    ((float2*)&hs[p][sr][sk])[0] = make_float2(hv.x, hv.y);
    ((float2*)&hs[p][sr][sk+2])[0] = make_float2(hv.z, hv.w);
    ((float2*)&ms[p][sr][sk])[0] = make_float2(mv.x, mv.y);
    ((float2*)&ms[p][sr][sk+2])[0] = make_float2(mv.z, mv.w);
    __syncthreads();           // also covers wred on first iteration

    // issue next chunk's global loads (overlap with compute below)
    if (k0 + 32 < D_H) {
      hv = *(const float4*)(hrow + k0 + 32);
      mv = *(const float4*)(mrow + k0 + 32);
    }

    #pragma unroll
    for (int g = 0; g < 8; ++g) {
      const int kk = 4 * g;
      const float wA = w2[k0 + kk + 0];
      const float wB = w2[k0 + kk + 1];
      const float wC = w2[k0 + kk + 2];
      const float wD = w2[k0 + kk + 3];
      float4 eh0 = *(const float4*)&hs[p][2*ti    ][kk];
      float4 eh1 = *(const float4*)&hs[p][2*ti + 1][kk];
      float4 em0 = *(const float4*)&ms[p][2*tj    ][kk];
      float4 em1 = *(const float4*)&ms[p][2*tj + 1][kk];

      #define TERM(EH, EM, ACC)                                        \
      {                                                                \
        float uA = fmaf((EH).x, (EM).x, 1.f);                          \
        float uB = fmaf((EH).y, (EM).y, 1.f);                          \
        float uC = fmaf((EH).z, (EM).z, 1.f);                          \
        float uD = fmaf((EH).w, (EM).w, 1.f);                          \
        float dAB = uA * uB, dCD = uC * uD;                            \
        float nAB = fmaf(wB, uA, wA * uB);                             \
        float nCD = fmaf(wD, uC, wC * uD);                             \
        float den = dAB * dCD;                                         \
        float num = fmaf(nCD, dAB, nAB * dCD);                         \
        ACC = fmaf(num, __builtin_amdgcn_rcpf(den), ACC);              \
      }
      TERM(eh0, em0, a00)
      TERM(eh0, em1, a01)
      TERM(eh1, em0, a10)
      TERM(eh1, em1, a11)
      #undef TERM
    }
    p ^= 1;
  }

  const float base = b2[0] + wred[0] + wred[1] + wred[2] + wred[3];
  const int i = i0 + 2*ti, j = j0 + 2*tj;
  float2 r0, r1;
  r0.x = fmaf(-2.f, a00, base); r0.y = fmaf(-2.f, a01, base);
  r1.x = fmaf(-2.f, a10, base); r1.y = fmaf(-2.f, a11, base);
  *(float2*)(out + (size_t)i       * 1024 + j) = r0;
  *(float2*)(out + (size_t)(i + 1) * 1024 + j) = r1;
}

extern "C" void kernel_launch(void* const* d_in, const int* in_sizes, int n_in,
                              void* d_out, int out_size, void* d_ws, size_t ws_size,
                              hipStream_t stream) {
  const float* V  = (const float*)d_in[0];
  const float* Wh = (const float*)d_in[1];
  const float* bh = (const float*)d_in[2];
  const float* Wm = (const float*)d_in[3];
  const float* bm = (const float*)d_in[4];
  const float* w2 = (const float*)d_in[5];
  const float* b2 = (const float*)d_in[6];
  float* outp = (float*)d_out;

  char* ws = (char*)d_ws;
  float* C = (float*)ws;                                 // 4 MB: Eh|Em
  if (ws_size >= (size_t)(8u << 20)) {
    _Float16* Vh = (_Float16*)(ws + (4u << 20));         // 2 MB
    _Float16* Wf = (_Float16*)(ws + (6u << 20));         // 2 MB
    cvt_kernel<<<dim3(1024), dim3(256), 0, stream>>>(V, Wh, Wm, Vh, Wf);
    proj_mfma_kernel<<<dim3(512), dim3(256), 0, stream>>>(Vh, Wf, bh, bm, C);
  } else {
    proj_kernel<<<dim3(256), dim3(256), 0, stream>>>(V, Wh, bh, Wm, bm, C);
  }
  score_kernel<<<dim3(1024), dim3(256), 0, stream>>>(C, w2, b2, outp);
}

// Round 6
// 85.059 us; speedup vs baseline: 1.0315x; 1.0315x over previous
//
#include <hip/hip_runtime.h>
#include <hip/hip_bf16.h>

#define D_IN  1024
#define D_H   512
#define L2E2  2.885390081777927f   // 2*log2(e)

typedef _Float16 half8 __attribute__((ext_vector_type(8)));
typedef _Float16 half4v __attribute__((ext_vector_type(4)));
typedef float f32x4 __attribute__((ext_vector_type(4)));

// ---------------------------------------------------------------------------
// cvt: V (1024x1024 f32) -> Vh f16 ; [Wh;Wm] (1024x1024 f32) -> Wf f16
// ---------------------------------------------------------------------------
__global__ __launch_bounds__(256) void cvt_kernel(
    const float* __restrict__ V,
    const float* __restrict__ Wh, const float* __restrict__ Wm,
    _Float16* __restrict__ Vh, _Float16* __restrict__ Wf)
{
  const int idx = blockIdx.x * 256 + threadIdx.x;   // 0..262143 float4s
  {
    float4 x = ((const float4*)V)[idx];
    half4v o = { (_Float16)x.x, (_Float16)x.y, (_Float16)x.z, (_Float16)x.w };
    ((half4v*)Vh)[idx] = o;
  }
  {
    const float4* p = (idx < 131072) ? ((const float4*)Wh + idx)
                                     : ((const float4*)Wm + (idx - 131072));
    float4 x = *p;
    half4v o = { (_Float16)x.x, (_Float16)x.y, (_Float16)x.z, (_Float16)x.w };
    ((half4v*)Wf)[idx] = o;
  }
}

// ---------------------------------------------------------------------------
// proj via MFMA. SPLIT=1: K halved across 2 planes (grid 512, 2 blocks/CU);
// half-clamp +-63, product re-clamped in score staging. SPLIT=0: full K,
// clamp +-15 (grid 256). 64x64 tile, 4 waves (2x2), 32x32/wave, 4 MFMA/step.
// ---------------------------------------------------------------------------
template<int SPLIT>
__global__ __launch_bounds__(256, 2) void proj_mfma_kernel(
    const _Float16* __restrict__ Vh, const _Float16* __restrict__ Wf,
    const float* __restrict__ bh, const float* __restrict__ bm,
    float* __restrict__ P0, float* __restrict__ P1)
{
  const int tid  = threadIdx.x;
  const int lane = tid & 63;
  const int wid  = tid >> 6;          // 0..3
  const int wi   = wid >> 1, wj = wid & 1;
  const int tz   = SPLIT ? (blockIdx.x >> 8) : 0;
  const int tb   = blockIdx.x & 255;
  const int i0   = (tb & 15) * 64;
  const int j0   = (tb >> 4) * 64;
  const int r16  = lane & 15;
  const int kg   = lane >> 4;         // k-group 0..3
  const int kb   = tz * 512;
  const int KLEN = SPLIT ? 512 : 1024;

  const _Float16* A0 = Vh + (size_t)(i0 + 32*wi + r16) * 1024 + kb + kg*8;
  const _Float16* A1 = A0 + 16 * 1024;
  const _Float16* B0 = Wf + (size_t)(j0 + 32*wj + r16) * 1024 + kb + kg*8;
  const _Float16* B1 = B0 + 16 * 1024;

  f32x4 acc00 = {0.f,0.f,0.f,0.f}, acc01 = acc00, acc10 = acc00, acc11 = acc00;
  #pragma unroll 4
  for (int k0 = 0; k0 < KLEN; k0 += 32) {
    half8 a0 = *(const half8*)(A0 + k0);
    half8 a1 = *(const half8*)(A1 + k0);
    half8 b0 = *(const half8*)(B0 + k0);
    half8 b1 = *(const half8*)(B1 + k0);
    acc00 = __builtin_amdgcn_mfma_f32_16x16x32_f16(a0, b0, acc00, 0, 0, 0);
    acc01 = __builtin_amdgcn_mfma_f32_16x16x32_f16(a0, b1, acc01, 0, 0, 0);
    acc10 = __builtin_amdgcn_mfma_f32_16x16x32_f16(a1, b0, acc10, 0, 0, 0);
    acc11 = __builtin_amdgcn_mfma_f32_16x16x32_f16(a1, b1, acc11, 0, 0, 0);
  }

  const float* biasp = (j0 < D_H) ? (bh + j0) : (bm + (j0 - D_H));
  float* Pz = (SPLIT && tz) ? P1 : P0;
  const float CL = SPLIT ? 63.f : 15.f;
  // C/D layout (m89-verified): col = lane&15, row = (lane>>4)*4 + reg
  #pragma unroll
  for (int fi = 0; fi < 2; ++fi) {
    #pragma unroll
    for (int fj = 0; fj < 2; ++fj) {
      const f32x4 acc = (fi == 0) ? (fj == 0 ? acc00 : acc01)
                                  : (fj == 0 ? acc10 : acc11);
      const int jl = 32*wj + 16*fj + r16;
      const float bias = (tz == 0) ? biasp[jl] : 0.f;
      #pragma unroll
      for (int rr = 0; rr < 4; ++rr) {
        const int il = 32*wi + 16*fi + 4*kg + rr;
        float x = (acc[rr] + bias) * L2E2;
        x = fminf(fmaxf(x, -CL), CL);
        Pz[(size_t)(i0 + il) * 1024 + j0 + jl] = __builtin_amdgcn_exp2f(x);
      }
    }
  }
}

// ---------------------------------------------------------------------------
// proj fallback (fp32 vector GEMM) when ws is too small for f16 staging.
// ---------------------------------------------------------------------------
__global__ __launch_bounds__(256) void proj_kernel(
    const float* __restrict__ V,
    const float* __restrict__ Wh, const float* __restrict__ bh,
    const float* __restrict__ Wm, const float* __restrict__ bm,
    float* __restrict__ C)
{
  __shared__ float As[16][68];
  __shared__ float Bs[16][68];

  const int tid = threadIdx.x;
  const int i0  = (blockIdx.x & 15) * 64, j0 = (blockIdx.x >> 4) * 64;
  const int ti  = tid >> 4, tj = tid & 15;
  const int sr  = tid >> 2;
  const int sk  = (tid & 3) << 2;

  const float* Wbase = (j0 < D_H) ? (Wh + (size_t)j0 * D_IN)
                                  : (Wm + (size_t)(j0 - D_H) * D_IN);
  const float* biasp = (j0 < D_H) ? (bh + j0) : (bm + (j0 - D_H));

  const float* arow = V     + (size_t)(i0 + sr) * D_IN + sk;
  const float* brow = Wbase + (size_t)sr        * D_IN + sk;

  float acc[4][4] = {};
  for (int k0 = 0; k0 < D_IN; k0 += 16) {
    float4 av = *(const float4*)(arow + k0);
    float4 bv = *(const float4*)(brow + k0);
    As[sk+0][sr] = av.x; As[sk+1][sr] = av.y; As[sk+2][sr] = av.z; As[sk+3][sr] = av.w;
    Bs[sk+0][sr] = bv.x; Bs[sk+1][sr] = bv.y; Bs[sk+2][sr] = bv.z; Bs[sk+3][sr] = bv.w;
    __syncthreads();
    #pragma unroll
    for (int kk = 0; kk < 16; ++kk) {
      float4 a = *(const float4*)&As[kk][4*ti];
      float4 b = *(const float4*)&Bs[kk][4*tj];
      #pragma unroll
      for (int x = 0; x < 4; ++x)
        #pragma unroll
        for (int y = 0; y < 4; ++y)
          acc[x][y] = fmaf((&a.x)[x], (&b.x)[y], acc[x][y]);
    }
    __syncthreads();
  }

  const int jl = 4 * tj;
  #pragma unroll
  for (int aa = 0; aa < 4; ++aa) {
    const int i = i0 + 4*ti + aa;
    float4 o;
    #pragma unroll
    for (int bb = 0; bb < 4; ++bb) {
      float x = (acc[aa][bb] + biasp[jl+bb]) * L2E2;
      x = fminf(fmaxf(x, -15.f), 15.f);
      (&o.x)[bb] = __builtin_amdgcn_exp2f(x);
    }
    *(float4*)(C + (size_t)i * 1024 + j0 + jl) = o;
  }
}

// ---------------------------------------------------------------------------
// score: out[i][j] = b2 + sum(w2) - 2 * sum_k w2[k]/(1 + Eh[i,k]*Em[j,k])
// 64x32 tile (i x j), 512 blocks (2/CU, 8 waves/CU), 4x2 strided outputs
// per thread (i = ti+16a, j = tj+16c). LDS stride 34, all-b64 accesses:
// em reads conflict-free, eh reads broadcast. 4-way k-fold, dbuf, 1 barrier.
// SPLIT: staged value = clamp(P0*P1, 2^-15, 2^15).
// ---------------------------------------------------------------------------
template<int SPLIT>
__global__ __launch_bounds__(256, 2) void score_kernel(
    const float* __restrict__ P0, const float* __restrict__ P1,
    const float* __restrict__ w2, const float* __restrict__ b2,
    float* __restrict__ out)
{
  __shared__ float hs[2][64][34];
  __shared__ float ms[2][32][34];
  __shared__ float wred[4];

  const int tid = threadIdx.x;
  const int bi  = blockIdx.x & 15;   // 16 i-tiles of 64
  const int bj  = blockIdx.x >> 4;   // 32 j-tiles of 32
  const int i0  = bi * 64, j0 = bj * 32;
  const int ti  = tid >> 4, tj = tid & 15;   // outputs: i0+ti+16a, j0+tj+16c

  const int sr  = tid >> 2;                  // hs staging row 0..63
  const int skq = tid & 3;                   // hs k-quad 0..3 (+4 for 2nd)
  const int smr = tid >> 3;                  // ms staging row 0..31
  const int smq = tid & 7;                   // ms k-quad 0..7

  // block-reduce sum(w2)
  float sw = 0.f;
  for (int t = tid; t < D_H; t += 256) sw += w2[t];
  #pragma unroll
  for (int off = 32; off > 0; off >>= 1) sw += __shfl_down(sw, off, 64);
  if ((tid & 63) == 0) wred[tid >> 6] = sw;

  const float* hp0 = P0 + (size_t)(i0 + sr) * 1024 + 4*skq;          // +k0, +16
  const float* mp0 = P0 + (size_t)(j0 + smr) * 1024 + D_H + 4*smq;   // +k0
  const float* hp1 = SPLIT ? (P1 + (size_t)(i0 + sr) * 1024 + 4*skq) : nullptr;
  const float* mp1 = SPLIT ? (P1 + (size_t)(j0 + smr) * 1024 + D_H + 4*smq) : nullptr;

  // prefetch chunk 0
  float4 ph0 = *(const float4*)(hp0);
  float4 ph1 = *(const float4*)(hp0 + 16);
  float4 pm0 = *(const float4*)(mp0);
  float4 qh0, qh1, qm0;
  if (SPLIT) {
    qh0 = *(const float4*)(hp1);
    qh1 = *(const float4*)(hp1 + 16);
    qm0 = *(const float4*)(mp1);
  }

  float acc[4][2] = {};
  int p = 0;

  #define CLAMP4(D, X, Y)                                              \
  {                                                                    \
    (D).x = fminf(fmaxf((X).x * (Y).x, 3.0517578125e-05f), 32768.f);   \
    (D).y = fminf(fmaxf((X).y * (Y).y, 3.0517578125e-05f), 32768.f);   \
    (D).z = fminf(fmaxf((X).z * (Y).z, 3.0517578125e-05f), 32768.f);   \
    (D).w = fminf(fmaxf((X).w * (Y).w, 3.0517578125e-05f), 32768.f);   \
  }

  for (int k0 = 0; k0 < D_H; k0 += 32) {
    // stage current chunk
    float4 vh0, vh1, vm0;
    if (SPLIT) { CLAMP4(vh0, ph0, qh0) CLAMP4(vh1, ph1, qh1) CLAMP4(vm0, pm0, qm0) }
    else       { vh0 = ph0; vh1 = ph1; vm0 = pm0; }
    *(float2*)&hs[p][sr][4*skq]      = make_float2(vh0.x, vh0.y);
    *(float2*)&hs[p][sr][4*skq + 2]  = make_float2(vh0.z, vh0.w);
    *(float2*)&hs[p][sr][4*skq + 16] = make_float2(vh1.x, vh1.y);
    *(float2*)&hs[p][sr][4*skq + 18] = make_float2(vh1.z, vh1.w);
    *(float2*)&ms[p][smr][4*smq]     = make_float2(vm0.x, vm0.y);
    *(float2*)&ms[p][smr][4*smq + 2] = make_float2(vm0.z, vm0.w);
    __syncthreads();          // also covers wred on first iteration

    // issue next chunk's loads (overlap with compute)
    if (k0 + 32 < D_H) {
      ph0 = *(const float4*)(hp0 + k0 + 32);
      ph1 = *(const float4*)(hp0 + k0 + 48);
      pm0 = *(const float4*)(mp0 + k0 + 32);
      if (SPLIT) {
        qh0 = *(const float4*)(hp1 + k0 + 32);
        qh1 = *(const float4*)(hp1 + k0 + 48);
        qm0 = *(const float4*)(mp1 + k0 + 32);
      }
    }

    #pragma unroll
    for (int g = 0; g < 8; ++g) {
      const int kk = 4 * g;
      const float wA = w2[k0 + kk + 0];
      const float wB = w2[k0 + kk + 1];
      const float wC = w2[k0 + kk + 2];
      const float wD = w2[k0 + kk + 3];
      float2 em_[2][2], eh_[4][2];
      #pragma unroll
      for (int c = 0; c < 2; ++c) {
        em_[c][0] = *(const float2*)&ms[p][tj + 16*c][kk];
        em_[c][1] = *(const float2*)&ms[p][tj + 16*c][kk + 2];
      }
      #pragma unroll
      for (int a = 0; a < 4; ++a) {
        eh_[a][0] = *(const float2*)&hs[p][ti + 16*a][kk];
        eh_[a][1] = *(const float2*)&hs[p][ti + 16*a][kk + 2];
      }
      #pragma unroll
      for (int a = 0; a < 4; ++a)
        #pragma unroll
        for (int c = 0; c < 2; ++c) {
          float uA = fmaf(eh_[a][0].x, em_[c][0].x, 1.f);
          float uB = fmaf(eh_[a][0].y, em_[c][0].y, 1.f);
          float uC = fmaf(eh_[a][1].x, em_[c][1].x, 1.f);
          float uD = fmaf(eh_[a][1].y, em_[c][1].y, 1.f);
          float dAB = uA * uB, dCD = uC * uD;
          float nAB = fmaf(wB, uA, wA * uB);
          float nCD = fmaf(wD, uC, wC * uD);
          float den = dAB * dCD;
          float num = fmaf(nCD, dAB, nAB * dCD);
          acc[a][c] = fmaf(num, __builtin_amdgcn_rcpf(den), acc[a][c]);
        }
    }
    p ^= 1;
  }
  #undef CLAMP4

  const float base = b2[0] + wred[0] + wred[1] + wred[2] + wred[3];
  #pragma unroll
  for (int a = 0; a < 4; ++a) {
    const int i = i0 + ti + 16*a;
    #pragma unroll
    for (int c = 0; c < 2; ++c) {
      const int j = j0 + tj + 16*c;
      out[(size_t)i * 1024 + j] = fmaf(-2.f, acc[a][c], base);
    }
  }
}

extern "C" void kernel_launch(void* const* d_in, const int* in_sizes, int n_in,
                              void* d_out, int out_size, void* d_ws, size_t ws_size,
                              hipStream_t stream) {
  const float* V  = (const float*)d_in[0];
  const float* Wh = (const float*)d_in[1];
  const float* bh = (const float*)d_in[2];
  const float* Wm = (const float*)d_in[3];
  const float* bm = (const float*)d_in[4];
  const float* w2 = (const float*)d_in[5];
  const float* b2 = (const float*)d_in[6];
  float* outp = (float*)d_out;

  char* ws = (char*)d_ws;
  float* P0 = (float*)ws;                                // 4 MB

  if (ws_size >= (size_t)(12u << 20)) {
    float*    P1 = (float*)(ws + (4u << 20));            // 4 MB
    _Float16* Vh = (_Float16*)(ws + (8u << 20));         // 2 MB
    _Float16* Wf = (_Float16*)(ws + (10u << 20));        // 2 MB
    cvt_kernel<<<dim3(1024), dim3(256), 0, stream>>>(V, Wh, Wm, Vh, Wf);
    proj_mfma_kernel<1><<<dim3(512), dim3(256), 0, stream>>>(Vh, Wf, bh, bm, P0, P1);
    score_kernel<1><<<dim3(512), dim3(256), 0, stream>>>(P0, P1, w2, b2, outp);
  } else if (ws_size >= (size_t)(8u << 20)) {
    _Float16* Vh = (_Float16*)(ws + (4u << 20));         // 2 MB
    _Float16* Wf = (_Float16*)(ws + (6u << 20));         // 2 MB
    cvt_kernel<<<dim3(1024), dim3(256), 0, stream>>>(V, Wh, Wm, Vh, Wf);
    proj_mfma_kernel<0><<<dim3(256), dim3(256), 0, stream>>>(Vh, Wf, bh, bm, P0, P0);
    score_kernel<0><<<dim3(512), dim3(256), 0, stream>>>(P0, P0, w2, b2, outp);
  } else {
    proj_kernel<<<dim3(256), dim3(256), 0, stream>>>(V, Wh, bh, Wm, bm, P0);
    score_kernel<0><<<dim3(512), dim3(256), 0, stream>>>(P0, P0, w2, b2, outp);
  }
}